// Round 5
// baseline (420.047 us; speedup 1.0000x reference)
//
#include <hip/hip_runtime.h>
#include <math.h>

// ---------------- problem constants ----------------
#define N_   32
#define NUP_ 16
#define M_   4
#define D_   128
#define K_   64
#define F_   32
#define H_   45
#define L_   3
#define LOG2_ 0.69314718055994530942f

typedef __attribute__((ext_vector_type(8))) short short8;
typedef __attribute__((ext_vector_type(4))) float float4v;

__device__ __forceinline__ float ssp(float v) {
    // softplus(v) - log(2) == log(0.5 + 0.5*e^v); ssp(0) == 0 exactly
    return __logf(fmaf(0.5f, __expf(v), 0.5f));
}

__device__ __forceinline__ unsigned short f2bf(float x) {   // RTNE, prep only
    unsigned int u = __float_as_uint(x);
    return (unsigned short)((u + 0x7FFFu + ((u >> 16) & 1u)) >> 16);
}

// pack two floats -> bf16x2 in ONE VALU op (RTNE)
__device__ __forceinline__ unsigned int cvtpk(float x, float y) {
    unsigned int r;
    asm("v_cvt_pk_bf16_f32 %0, %1, %2" : "=v"(r) : "v"(x), "v"(y));
    return r;
}

// ---------------- prep: pack all weights into MFMA B-fragment order ----------------
// w1B[lc][nt:3][512]   frag: k=(lane>>4)*8+jj (f), row/col idx = nt*16+(lane&15) (hidden)
//                      (A-frag and B-frag have identical lane maps for 16x16x32)
// w2B[lc][ks:2][nt:4][512]  B-frag: k=p, n=kout.  p-map for REGISTER-DIRECT stage 2
//                      (stage-1 swapped: lane q holds h = nt*16 + q*4 + r):
//                      p<32:  h = (j>>2)*16 + q*4 + (j&3)   (q=p>>3, j=p&7)
//                      p>=32, j<4: h = 32 + q*4 + j
//                      p==36: bias row (pairs with A-frag const 1.0); else zero
// gB [l][ks:6][nt:8][512]   k=c*64+kk, n=d
// hB [li:2][ks:4][nt2:4][512] k=p, d=(p&7)*16+(p>>3), n=kout   (hW layers 1,2)
// gbs[l][128] = sum_c gb[l][c][:]
__global__ __launch_bounds__(256) void prep_kernel(
    const float* __restrict__ wW1, const float* __restrict__ wb1_unused,
    const float* __restrict__ wW2, const float* __restrict__ wb2,
    const float* __restrict__ gW,  const float* __restrict__ hW,
    const float* __restrict__ gb,
    short* __restrict__ w1B, short* __restrict__ w2B,
    short* __restrict__ gB,  short* __restrict__ hB, float* __restrict__ gbs)
{
    int blk = blockIdx.x;
    int t = threadIdx.x;
    if (blk < 27) {                       // w1B
        int lc = blk / 3, nt = blk % 3;
        short* dst = w1B + (size_t)blk * 512;
        for (int idx = t; idx < 512; idx += 256) {
            int lane = idx >> 3, jj = idx & 7;
            int k = ((lane >> 4) << 3) + jj;
            int n = nt * 16 + (lane & 15);
            float v = (n < H_) ? wW1[((size_t)lc * H_ + n) * F_ + k] : 0.0f;
            dst[idx] = (short)f2bf(v);
        }
    } else if (blk < 99) {                // w2B (register-direct p-map)
        int b3 = blk - 27;
        int lc = b3 >> 3, rem = b3 & 7, ks = rem >> 2, nt = rem & 3;
        short* dst = w2B + (size_t)b3 * 512;
        for (int idx = t; idx < 512; idx += 256) {
            int lane = idx >> 3, jj = idx & 7;
            int p = ks * 32 + ((lane >> 4) << 3) + jj;
            int n = nt * 16 + (lane & 15);
            int q = (p & 31) >> 3, j = p & 7;
            float v;
            if (p < 32) {
                int u = (j >> 2) * 16 + q * 4 + (j & 3);    // h < 32, always valid
                v = wW2[((size_t)lc * K_ + n) * H_ + u];
            } else if (j < 4) {
                int u = 32 + q * 4 + j;
                v = (u < H_) ? wW2[((size_t)lc * K_ + n) * H_ + u] : 0.0f;
            } else if (p == 36) {
                v = wb2[(size_t)lc * K_ + n];
            } else v = 0.0f;
            dst[idx] = (short)f2bf(v);
        }
    } else if (blk < 243) {               // gB
        int g = blk - 99;
        int l = g / 48, rem = g % 48;     // rem = ks*8+nt
        short* dst = gB + (size_t)g * 512;
        for (int idx = t; idx < 512; idx += 256) {
            int lane = idx >> 3, jj = idx & 7;
            int k = (rem >> 3) * 32 + ((lane >> 4) << 3) + jj;  // 0..191
            int c = k >> 6, kk = k & 63;
            int n = ((rem & 7) * 16) + (lane & 15);
            dst[idx] = (short)f2bf(gW[(((size_t)l * 3 + c) * D_ + n) * K_ + kk]);
        }
    } else if (blk < 275) {               // hB
        int hh = blk - 243;
        int li = hh >> 4, rem = hh & 15;  // rem = ks*4+nt2
        short* dst = hB + (size_t)hh * 512;
        for (int idx = t; idx < 512; idx += 256) {
            int lane = idx >> 3, jj = idx & 7;
            int p = (rem >> 2) * 32 + ((lane >> 4) << 3) + jj;  // 0..127
            int d = (p & 7) * 16 + (p >> 3);
            int n = ((rem & 3) * 16) + (lane & 15);
            dst[idx] = (short)f2bf(hW[(((size_t)(li + 1)) * K_ + n) * D_ + d]);
        }
    } else {                              // gbs
        for (int idx = t; idx < 384; idx += 256) {
            int l = idx >> 7, d = idx & 127;
            gbs[idx] = gb[((size_t)l * 3 + 0) * D_ + d]
                     + gb[((size_t)l * 3 + 1) * D_ + d]
                     + gb[((size_t)l * 3 + 2) * D_ + d];
        }
    }
}

// ---------------- h0: layer-0 h is a single broadcast row ----------------
__global__ __launch_bounds__(64) void h0_kernel(
    const float* __restrict__ X, const float* __restrict__ hW,
    const float* __restrict__ hb, float* __restrict__ h0)
{
    int k = threadIdx.x;
    float a = hb[k];
    const float* w = hW + (size_t)k * D_;
    #pragma unroll 8
    for (int dd = 0; dd < D_; ++dd) a += w[dd] * X[dd];
    h0[k] = a;
}

// ---------------- MFMA edge kernel: 4 waves/WG, one (b,i) per wave ----------------
// Stage 1 computes S^T = W1 @ e^T (A=W1, B=e^T): lane (l16,quad) holds the 12
// hidden activations of edge l16 (h = nt*16 + quad*4 + r) IN REGISTERS — they
// feed stage 2's A-fragment directly, no LDS transpose.
// Stage-1 bias comes straight from wb1 (contiguous in h), guarded at h>=45.
// Nuclear tile: the block's 4 i's give 16 live rows -> one tile on wave 0.
#define WSTRIDE 68     // f32 words per wrow row
__global__ __launch_bounds__(256, 8) void edge_kernel(
    const float* __restrict__ ee, const float* __restrict__ en,
    const float* __restrict__ Y,
    const short* __restrict__ w1B, const float* __restrict__ wb1,
    const short* __restrict__ w2B,
    const float* __restrict__ h, const float* __restrict__ h0,
    unsigned short* __restrict__ zb, int l, int hmode)
{
    __shared__ float wrow[36 * WSTRIDE];          // 9792 B (h rows 0..31, Y rows 32..35)

    const int tid  = threadIdx.x;
    const int wv   = tid >> 6;
    const int lane = tid & 63;
    const int quad = lane >> 4;
    const int l16  = lane & 15;
    const int b    = blockIdx.x >> 3;
    const int i    = ((blockIdx.x & 7) << 2) + wv;
    const int bi   = (b << 5) + i;

    // ---- stage wrow cooperatively ----
    {
        int row = tid >> 3;
        int col = (tid & 7) * 8;
        const float* src = hmode ? (h + ((size_t)(b * N_ + row)) * K_ + col) : (h0 + col);
        float4 v0 = *(const float4*)(src);
        float4 v1 = *(const float4*)(src + 4);
        *(float4*)(wrow + row * WSTRIDE + col)     = v0;
        *(float4*)(wrow + row * WSTRIDE + col + 4) = v1;
        if (tid < 32) {
            int r2 = tid >> 3, o2 = (tid & 7) * 8;
            float4 y0 = *(const float4*)(Y + (size_t)r2 * K_ + o2);
            float4 y1 = *(const float4*)(Y + (size_t)r2 * K_ + o2 + 4);
            *(float4*)(wrow + (32 + r2) * WSTRIDE + o2)     = y0;
            *(float4*)(wrow + (32 + r2) * WSTRIDE + o2 + 4) = y1;
        }
    }
    __syncthreads();

    const int cA  = (i < NUP_) ? 0 : 1;
    const int tti = i >> 4;                        // tile holding self-row
    const int sil = i & 15;                        // self-row lane
    const int hq  = quad * 4;
    const unsigned int biasu = (quad == 0) ? 0x00003F80u : 0u;   // bf16 1.0 @ p=36

    // ================= electron tiles =================
    #pragma unroll
    for (int t = 0; t < 2; ++t) {
        const int c  = (t == 0) ? cA : 1 - cA;
        const int lc = l * 3 + c;
        const float* wlc = wb1 + (size_t)lc * H_;

        // ---- B-frag (e^T): 8 consecutive f of this lane's edge row ----
        const float* ep = ee + (((size_t)bi * N_) + t * 16 + l16) * F_ + quad * 8;
        float4 fa = *(const float4*)(ep);
        float4 fb = *(const float4*)(ep + 4);
        union { short8 s; unsigned int u[4]; } E;
        E.u[0] = cvtpk(fa.x, fa.y); E.u[1] = cvtpk(fa.z, fa.w);
        E.u[2] = cvtpk(fb.x, fb.y); E.u[3] = cvtpk(fb.z, fb.w);

        // ---- stage-1 bias (h contiguous in wb1; guard h>=45, clamp address) ----
        const bool g3 = (hq < 12);
        float4v acc1[3];
        acc1[0] = (float4v){wlc[hq], wlc[hq + 1], wlc[hq + 2], wlc[hq + 3]};
        acc1[1] = (float4v){wlc[16 + hq], wlc[17 + hq], wlc[18 + hq], wlc[19 + hq]};
        {
            float b1 = wlc[g3 ? (33 + hq) : 0];
            float b2 = wlc[g3 ? (34 + hq) : 0];
            float b3 = wlc[g3 ? (35 + hq) : 0];
            acc1[2] = (float4v){wlc[32 + hq], g3 ? b1 : 0.0f, g3 ? b2 : 0.0f, g3 ? b3 : 0.0f};
        }

        // ---- stage 1 swapped: D[h][edge] ----
        #pragma unroll
        for (int nt = 0; nt < 3; ++nt) {
            short8 wf = *(const short8*)(w1B + (((size_t)lc * 3 + nt) << 9) + (lane << 3));
            acc1[nt] = __builtin_amdgcn_mfma_f32_16x16x32_bf16(wf, E.s, acc1[nt], 0, 0, 0);
        }

        // ---- ssp + pack straight into stage-2 A-frags (no LDS) ----
        union { short8 s; unsigned int u[4]; } A0, A1;
        A0.u[0] = cvtpk(ssp(acc1[0][0]), ssp(acc1[0][1]));
        A0.u[1] = cvtpk(ssp(acc1[0][2]), ssp(acc1[0][3]));
        A0.u[2] = cvtpk(ssp(acc1[1][0]), ssp(acc1[1][1]));
        A0.u[3] = cvtpk(ssp(acc1[1][2]), ssp(acc1[1][3]));
        A1.u[0] = cvtpk(ssp(acc1[2][0]), ssp(acc1[2][1]));
        A1.u[1] = cvtpk(ssp(acc1[2][2]), ssp(acc1[2][3]));
        A1.u[2] = biasu;
        A1.u[3] = 0u;
        const bool deadl = (t == tti) && (l16 == sil);   // self-edge: zero whole row
        if (deadl) {
            A0.u[0] = 0u; A0.u[1] = 0u; A0.u[2] = 0u; A0.u[3] = 0u;
            A1.u[0] = 0u; A1.u[1] = 0u; A1.u[2] = 0u;
        }

        // ---- stage 2: two K-steps, bias via p=36 slot ----
        float4v acc2[4];
        #pragma unroll
        for (int nt = 0; nt < 4; ++nt) acc2[nt] = (float4v){0.f, 0.f, 0.f, 0.f};
        #pragma unroll
        for (int nt = 0; nt < 4; ++nt) {
            short8 bf0 = *(const short8*)(w2B + ((((size_t)lc * 2 + 0) * 4 + nt) << 9) + (lane << 3));
            acc2[nt] = __builtin_amdgcn_mfma_f32_16x16x32_bf16(A0.s, bf0, acc2[nt], 0, 0, 0);
            short8 bf1 = *(const short8*)(w2B + ((((size_t)lc * 2 + 1) * 4 + nt) << 9) + (lane << 3));
            acc2[nt] = __builtin_amdgcn_mfma_f32_16x16x32_bf16(A1.s, bf1, acc2[nt], 0, 0, 0);
        }

        // ---- epilogue: msg * h(j,k), sum over rows — unmasked (dead row is 0) ----
        float p0 = 0.f, p1 = 0.f, p2 = 0.f, p3 = 0.f;
        #pragma unroll
        for (int r = 0; r < 4; ++r) {
            const int jrow = t * 16 + quad * 4 + r;
            const float* wr = wrow + jrow * WSTRIDE + l16;
            p0 += acc2[0][r] * wr[0];
            p1 += acc2[1][r] * wr[16];
            p2 += acc2[2][r] * wr[32];
            p3 += acc2[3][r] * wr[48];
        }

        // ---- butterfly reduce with value swap: 3 shuffles, no final select ----
        const bool qlo = (quad & 1) != 0;
        const bool qhi = (quad & 2) != 0;
        float u  = qlo ? p1 : p0;
        float us = qlo ? p0 : p1;
        u += __shfl_xor(us, 16);
        float w  = qlo ? p3 : p2;
        float ws = qlo ? p2 : p3;
        w += __shfl_xor(ws, 16);
        float v  = qhi ? w : u;
        float vs = qhi ? u : w;
        v += __shfl_xor(vs, 32);

        zb[(size_t)bi * 192 + c * 64 + lane] = (unsigned short)cvtpk(v, v);
    }

    // ================= nuclear tile: wave 0 only, 4 i's x 4 m's =================
    if (wv == 0) {
        const int lc = l * 3 + 2;
        const float* wlc = wb1 + (size_t)lc * H_;

        // edge row l16 = 4*local_i + m  ->  en[bi*4 + l16]
        const float* np = en + ((size_t)bi * M_ + l16) * F_ + quad * 8;
        float4 fa = *(const float4*)(np);
        float4 fb = *(const float4*)(np + 4);
        union { short8 s; unsigned int u[4]; } E;
        E.u[0] = cvtpk(fa.x, fa.y); E.u[1] = cvtpk(fa.z, fa.w);
        E.u[2] = cvtpk(fb.x, fb.y); E.u[3] = cvtpk(fb.z, fb.w);

        const bool g3 = (hq < 12);
        float4v acc1[3];
        acc1[0] = (float4v){wlc[hq], wlc[hq + 1], wlc[hq + 2], wlc[hq + 3]};
        acc1[1] = (float4v){wlc[16 + hq], wlc[17 + hq], wlc[18 + hq], wlc[19 + hq]};
        {
            float b1 = wlc[g3 ? (33 + hq) : 0];
            float b2 = wlc[g3 ? (34 + hq) : 0];
            float b3 = wlc[g3 ? (35 + hq) : 0];
            acc1[2] = (float4v){wlc[32 + hq], g3 ? b1 : 0.0f, g3 ? b2 : 0.0f, g3 ? b3 : 0.0f};
        }
        #pragma unroll
        for (int nt = 0; nt < 3; ++nt) {
            short8 wf = *(const short8*)(w1B + (((size_t)lc * 3 + nt) << 9) + (lane << 3));
            acc1[nt] = __builtin_amdgcn_mfma_f32_16x16x32_bf16(wf, E.s, acc1[nt], 0, 0, 0);
        }

        union { short8 s; unsigned int u[4]; } A0, A1;
        A0.u[0] = cvtpk(ssp(acc1[0][0]), ssp(acc1[0][1]));
        A0.u[1] = cvtpk(ssp(acc1[0][2]), ssp(acc1[0][3]));
        A0.u[2] = cvtpk(ssp(acc1[1][0]), ssp(acc1[1][1]));
        A0.u[3] = cvtpk(ssp(acc1[1][2]), ssp(acc1[1][3]));
        A1.u[0] = cvtpk(ssp(acc1[2][0]), ssp(acc1[2][1]));
        A1.u[1] = cvtpk(ssp(acc1[2][2]), ssp(acc1[2][3]));
        A1.u[2] = biasu;
        A1.u[3] = 0u;

        float4v acc2[4];
        #pragma unroll
        for (int nt = 0; nt < 4; ++nt) acc2[nt] = (float4v){0.f, 0.f, 0.f, 0.f};
        #pragma unroll
        for (int nt = 0; nt < 4; ++nt) {
            short8 bf0 = *(const short8*)(w2B + ((((size_t)lc * 2 + 0) * 4 + nt) << 9) + (lane << 3));
            acc2[nt] = __builtin_amdgcn_mfma_f32_16x16x32_bf16(A0.s, bf0, acc2[nt], 0, 0, 0);
            short8 bf1 = *(const short8*)(w2B + ((((size_t)lc * 2 + 1) * 4 + nt) << 9) + (lane << 3));
            acc2[nt] = __builtin_amdgcn_mfma_f32_16x16x32_bf16(A1.s, bf1, acc2[nt], 0, 0, 0);
        }

        // acc2[nt][r] = msg[row=quad*4+r][col=nt*16+l16]; row -> (local_i=quad, m=r)
        float p0 = 0.f, p1 = 0.f, p2 = 0.f, p3 = 0.f;
        #pragma unroll
        for (int r = 0; r < 4; ++r) {
            const float* wr = wrow + (32 + r) * WSTRIDE + l16;
            p0 += acc2[0][r] * wr[0];
            p1 += acc2[1][r] * wr[16];
            p2 += acc2[2][r] * wr[32];
            p3 += acc2[3][r] * wr[48];
        }
        unsigned short* zo = zb + (size_t)(bi + quad) * 192 + 128 + l16;
        zo[0]  = (unsigned short)cvtpk(p0, p0);
        zo[16] = (unsigned short)cvtpk(p1, p1);
        zo[32] = (unsigned short)cvtpk(p2, p2);
        zo[48] = (unsigned short)cvtpk(p3, p3);
    }
}

// ---------------- MFMA fuse: x += Z@Gcat^T + gbs; h_next = x@hW^T + hb ----------------
// Wave pairs split the output-column dim: half = wv&1 handles nt0 = half*4 .. +3
// of the x-GEMM and nt2 = half*2 .. +1 of the h-GEMM. 2 row-groups per block.
#define HXS 136   // shorts per hx row
__global__ __launch_bounds__(256) void fuse_kernel(
    const unsigned short* __restrict__ zb, const short* __restrict__ gB,
    const float* __restrict__ gbs, const float* __restrict__ X,
    const short* __restrict__ hB, const float* __restrict__ hb,
    float* __restrict__ xout, float* __restrict__ hout,
    int l, int first, int compute_h)
{
    __shared__ short hx_s[2][16 * HXS];    // 8704 B

    const int tid  = threadIdx.x;
    const int wv   = tid >> 6;
    const int lane = tid & 63;
    const int quad = lane >> 4;
    const int l16  = lane & 15;
    const int pair = wv >> 1;
    const int half = wv & 1;
    const int nt0  = half * 4;
    const int bi0  = (blockIdx.x * 2 + pair) * 16;

    // ---- Z @ Gcat^T : 6 K-steps x 4 column tiles (this wave's half) ----
    float4v ax[4];
    #pragma unroll
    for (int nt = 0; nt < 4; ++nt) ax[nt] = (float4v){0.f, 0.f, 0.f, 0.f};
    const short* gb_ = gB + (size_t)l * 48 * 512;
    const short* zrow = (const short*)zb + ((size_t)(bi0 + l16)) * 192;
    #pragma unroll
    for (int ks = 0; ks < 6; ++ks) {
        short8 az = *(const short8*)(zrow + ks * 32 + quad * 8);
        #pragma unroll
        for (int nt = 0; nt < 4; ++nt) {
            short8 bf = *(const short8*)(gb_ + (((size_t)ks * 8 + nt0 + nt) << 9) + (lane << 3));
            ax[nt] = __builtin_amdgcn_mfma_f32_16x16x32_bf16(az, bf, ax[nt], 0, 0, 0);
        }
    }

    // ---- epilogue: residual + biases, store x, pack bf16 half-rows for h-GEMM ----
    float gv[4], xb[4];
    #pragma unroll
    for (int nt = 0; nt < 4; ++nt) {
        gv[nt] = gbs[(size_t)l * D_ + (nt0 + nt) * 16 + l16];
        if (first) xb[nt] = X[(nt0 + nt) * 16 + l16];
    }
    short* hx = hx_s[pair];
    #pragma unroll
    for (int r = 0; r < 4; ++r) {
        int row = quad * 4 + r;
        size_t gi = ((size_t)(bi0 + row)) * D_ + l16;
        float xv[4];
        #pragma unroll
        for (int nt = 0; nt < 4; ++nt) {
            float xo = (first ? xb[nt] : xout[gi + (nt0 + nt) * 16]) + gv[nt] + ax[nt][r];
            xout[gi + (nt0 + nt) * 16] = xo;
            xv[nt] = xo;
        }
        if (compute_h) {
            uint2 P;
            P.x = cvtpk(xv[0], xv[1]);
            P.y = cvtpk(xv[2], xv[3]);
            *(uint2*)(hx + row * HXS + 8 * l16 + 4 * half) = P;
        }
    }
    if (!compute_h) return;
    __syncthreads();

    // ---- h_next = x @ hW^T : 4 K-steps x 2 column tiles (this wave's half) ----
    float4v ah[2];
    #pragma unroll
    for (int nt = 0; nt < 2; ++nt) ah[nt] = (float4v){0.f, 0.f, 0.f, 0.f};
    const short* hb_ = hB + (size_t)l * 16 * 512;
    #pragma unroll
    for (int ks = 0; ks < 4; ++ks) {
        short8 a = *(const short8*)(hx + l16 * HXS + ks * 32 + quad * 8);
        #pragma unroll
        for (int nt = 0; nt < 2; ++nt) {
            short8 bf = *(const short8*)(hb_ + (((size_t)ks * 4 + half * 2 + nt) << 9) + (lane << 3));
            ah[nt] = __builtin_amdgcn_mfma_f32_16x16x32_bf16(a, bf, ah[nt], 0, 0, 0);
        }
    }
    float hbv[2];
    #pragma unroll
    for (int nt = 0; nt < 2; ++nt) hbv[nt] = hb[((size_t)(l + 1)) * K_ + (half * 2 + nt) * 16 + l16];
    #pragma unroll
    for (int nt = 0; nt < 2; ++nt)
        #pragma unroll
        for (int r = 0; r < 4; ++r)
            hout[((size_t)(bi0 + quad * 4 + r)) * K_ + (half * 2 + nt) * 16 + l16] = ah[nt][r] + hbv[nt];
}

// ---------------- launch ----------------
extern "C" void kernel_launch(void* const* d_in, const int* in_sizes, int n_in,
                              void* d_out, int out_size, void* d_ws, size_t ws_size,
                              hipStream_t stream)
{
    const float* ee  = (const float*)d_in[0];
    const float* en  = (const float*)d_in[1];
    const float* X   = (const float*)d_in[2];
    const float* Y   = (const float*)d_in[3];
    const float* wW1 = (const float*)d_in[4];
    const float* wb1 = (const float*)d_in[5];
    const float* wW2 = (const float*)d_in[6];
    const float* wb2 = (const float*)d_in[7];
    const float* hW  = (const float*)d_in[8];
    const float* hb  = (const float*)d_in[9];
    const float* gW  = (const float*)d_in[10];
    const float* gb  = (const float*)d_in[11];
    float* xout = (float*)d_out;

    // workspace carve (byte offsets, all 16B-aligned) — footprint unchanged
    char* ws = (char*)d_ws;
    float*          h   = (float*)(ws);                         // 8,388,608 B
    unsigned short* zb  = (unsigned short*)(ws + 8388608);      // 12,582,912 B
    float*          h0  = (float*)(ws + 8388608 + 12582912);    // 256 B
    short*          w1B = (short*)(ws + 20971520 + 256);        // 27,648 B
    short*          w2B = w1B + (size_t)27 * 512;               // 73,728 B
    short*          gB  = w2B + (size_t)72 * 512;               // 147,456 B
    short*          hB  = gB  + (size_t)144 * 512;              // 32,768 B
    float*          gbs = (float*)(hB + (size_t)32 * 512);      // 1,536 B

    prep_kernel<<<276, 256, 0, stream>>>(wW1, wb1, wW2, wb2, gW, hW, gb,
                                         w1B, w2B, gB, hB, gbs);
    h0_kernel<<<1, 64, 0, stream>>>(X, hW, hb, h0);

    // layer 0
    edge_kernel<<<8192, 256, 0, stream>>>(ee, en, Y, w1B, wb1, w2B, h, h0, zb, 0, 0);
    fuse_kernel<<<1024, 256, 0, stream>>>(zb, gB, gbs, X, hB, hb, xout, h, 0, 1, 1);
    // layer 1
    edge_kernel<<<8192, 256, 0, stream>>>(ee, en, Y, w1B, wb1, w2B, h, h0, zb, 1, 1);
    fuse_kernel<<<1024, 256, 0, stream>>>(zb, gB, gbs, X, hB, hb, xout, h, 1, 0, 1);
    // layer 2
    edge_kernel<<<8192, 256, 0, stream>>>(ee, en, Y, w1B, wb1, w2B, h, h0, zb, 2, 1);
    fuse_kernel<<<1024, 256, 0, stream>>>(zb, gB, gbs, X, hB, hb, xout, h, 2, 0, 0);
}

// Round 6
// 401.796 us; speedup vs baseline: 1.0454x; 1.0454x over previous
//
#include <hip/hip_runtime.h>
#include <math.h>

// ---------------- problem constants ----------------
#define N_   32
#define NUP_ 16
#define M_   4
#define D_   128
#define K_   64
#define F_   32
#define H_   45
#define L_   3
#define LOG2_ 0.69314718055994530942f

typedef __attribute__((ext_vector_type(8))) short short8;
typedef __attribute__((ext_vector_type(4))) float float4v;

__device__ __forceinline__ float ssp(float v) {
    // softplus(v) - log(2) == log(0.5 + 0.5*e^v); ssp(0) == 0 exactly
    return __logf(fmaf(0.5f, __expf(v), 0.5f));
}

__device__ __forceinline__ unsigned short f2bf(float x) {   // RTNE, prep only
    unsigned int u = __float_as_uint(x);
    return (unsigned short)((u + 0x7FFFu + ((u >> 16) & 1u)) >> 16);
}

// pack two floats -> bf16x2 in ONE VALU op (RTNE)
__device__ __forceinline__ unsigned int cvtpk(float x, float y) {
    unsigned int r;
    asm("v_cvt_pk_bf16_f32 %0, %1, %2" : "=v"(r) : "v"(x), "v"(y));
    return r;
}

// ---------------- prep: pack all weights into MFMA B-fragment order ----------------
// w1B[lc][nt:3][512]   frag: k=(lane>>4)*8+jj (f), row/col idx = nt*16+(lane&15) (hidden)
//                      (A-frag and B-frag have identical lane maps for 16x16x32)
// w2B[lc][ks:2][nt:4][512]  B-frag: k=p, n=kout.  p-map for REGISTER-DIRECT stage 2
//                      (stage-1 swapped: lane q holds h = nt*16 + q*4 + r):
//                      p<32:  h = (j>>2)*16 + q*4 + (j&3)   (q=p>>3, j=p&7)
//                      p>=32, j<4: h = 32 + q*4 + j
//                      p==36: bias row (pairs with A-frag const 1.0); else zero
// gB [l][ks:6][nt:8][512]   k=c*64+kk, n=d
// hB [li:2][ks:4][nt2:4][512] k=p, d=(p&7)*16+(p>>3), n=kout   (hW layers 1,2)
// gbs[l][128] = sum_c gb[l][c][:]
__global__ __launch_bounds__(256) void prep_kernel(
    const float* __restrict__ wW1, const float* __restrict__ wb1_unused,
    const float* __restrict__ wW2, const float* __restrict__ wb2,
    const float* __restrict__ gW,  const float* __restrict__ hW,
    const float* __restrict__ gb,
    short* __restrict__ w1B, short* __restrict__ w2B,
    short* __restrict__ gB,  short* __restrict__ hB, float* __restrict__ gbs)
{
    int blk = blockIdx.x;
    int t = threadIdx.x;
    if (blk < 27) {                       // w1B
        int lc = blk / 3, nt = blk % 3;
        short* dst = w1B + (size_t)blk * 512;
        for (int idx = t; idx < 512; idx += 256) {
            int lane = idx >> 3, jj = idx & 7;
            int k = ((lane >> 4) << 3) + jj;
            int n = nt * 16 + (lane & 15);
            float v = (n < H_) ? wW1[((size_t)lc * H_ + n) * F_ + k] : 0.0f;
            dst[idx] = (short)f2bf(v);
        }
    } else if (blk < 99) {                // w2B (register-direct p-map)
        int b3 = blk - 27;
        int lc = b3 >> 3, rem = b3 & 7, ks = rem >> 2, nt = rem & 3;
        short* dst = w2B + (size_t)b3 * 512;
        for (int idx = t; idx < 512; idx += 256) {
            int lane = idx >> 3, jj = idx & 7;
            int p = ks * 32 + ((lane >> 4) << 3) + jj;
            int n = nt * 16 + (lane & 15);
            int q = (p & 31) >> 3, j = p & 7;
            float v;
            if (p < 32) {
                int u = (j >> 2) * 16 + q * 4 + (j & 3);    // h < 32, always valid
                v = wW2[((size_t)lc * K_ + n) * H_ + u];
            } else if (j < 4) {
                int u = 32 + q * 4 + j;
                v = (u < H_) ? wW2[((size_t)lc * K_ + n) * H_ + u] : 0.0f;
            } else if (p == 36) {
                v = wb2[(size_t)lc * K_ + n];
            } else v = 0.0f;
            dst[idx] = (short)f2bf(v);
        }
    } else if (blk < 243) {               // gB
        int g = blk - 99;
        int l = g / 48, rem = g % 48;     // rem = ks*8+nt
        short* dst = gB + (size_t)g * 512;
        for (int idx = t; idx < 512; idx += 256) {
            int lane = idx >> 3, jj = idx & 7;
            int k = (rem >> 3) * 32 + ((lane >> 4) << 3) + jj;  // 0..191
            int c = k >> 6, kk = k & 63;
            int n = ((rem & 7) * 16) + (lane & 15);
            dst[idx] = (short)f2bf(gW[(((size_t)l * 3 + c) * D_ + n) * K_ + kk]);
        }
    } else if (blk < 275) {               // hB
        int hh = blk - 243;
        int li = hh >> 4, rem = hh & 15;  // rem = ks*4+nt2
        short* dst = hB + (size_t)hh * 512;
        for (int idx = t; idx < 512; idx += 256) {
            int lane = idx >> 3, jj = idx & 7;
            int p = (rem >> 2) * 32 + ((lane >> 4) << 3) + jj;  // 0..127
            int d = (p & 7) * 16 + (p >> 3);
            int n = ((rem & 3) * 16) + (lane & 15);
            dst[idx] = (short)f2bf(hW[(((size_t)(li + 1)) * K_ + n) * D_ + d]);
        }
    } else {                              // gbs
        for (int idx = t; idx < 384; idx += 256) {
            int l = idx >> 7, d = idx & 127;
            gbs[idx] = gb[((size_t)l * 3 + 0) * D_ + d]
                     + gb[((size_t)l * 3 + 1) * D_ + d]
                     + gb[((size_t)l * 3 + 2) * D_ + d];
        }
    }
}

// ---------------- h0: layer-0 h is a single broadcast row ----------------
__global__ __launch_bounds__(64) void h0_kernel(
    const float* __restrict__ X, const float* __restrict__ hW,
    const float* __restrict__ hb, float* __restrict__ h0)
{
    int k = threadIdx.x;
    float a = hb[k];
    const float* w = hW + (size_t)k * D_;
    #pragma unroll 8
    for (int dd = 0; dd < D_; ++dd) a += w[dd] * X[dd];
    h0[k] = a;
}

// ---------------- MFMA edge kernel: 4 waves/WG, one (b,i) per wave ----------------
// Stage 1 computes S^T = W1 @ e^T (A=W1, B=e^T): lane (l16,quad) holds the 12
// hidden activations of edge l16 (h = nt*16 + quad*4 + r) IN REGISTERS — they
// feed stage 2's A-fragment directly, no LDS transpose.
// launch_bounds(256,6): 6 waves/SIMD -> ~84 VGPR cap. (256,8) forced a 64-VGPR
// cap that SPILLED the register-direct form (round 5: WRITE_SIZE 12->45 MB).
// Achieved occupancy has never exceeded ~23 waves/CU, so 24-wave cap is free.
#define WSTRIDE 68     // f32 words per wrow row
__global__ __launch_bounds__(256, 6) void edge_kernel(
    const float* __restrict__ ee, const float* __restrict__ en,
    const float* __restrict__ Y,
    const short* __restrict__ w1B, const float* __restrict__ wb1,
    const short* __restrict__ w2B,
    const float* __restrict__ h, const float* __restrict__ h0,
    unsigned short* __restrict__ zb, int l, int hmode)
{
    __shared__ float wrow[36 * WSTRIDE];          // 9792 B (h rows 0..31, Y rows 32..35)

    const int tid  = threadIdx.x;
    const int wv   = tid >> 6;
    const int lane = tid & 63;
    const int quad = lane >> 4;
    const int l16  = lane & 15;
    const int b    = blockIdx.x >> 3;
    const int i    = ((blockIdx.x & 7) << 2) + wv;
    const int bi   = (b << 5) + i;

    // ---- stage wrow cooperatively ----
    {
        int row = tid >> 3;
        int col = (tid & 7) * 8;
        const float* src = hmode ? (h + ((size_t)(b * N_ + row)) * K_ + col) : (h0 + col);
        float4 v0 = *(const float4*)(src);
        float4 v1 = *(const float4*)(src + 4);
        *(float4*)(wrow + row * WSTRIDE + col)     = v0;
        *(float4*)(wrow + row * WSTRIDE + col + 4) = v1;
        if (tid < 32) {
            int r2 = tid >> 3, o2 = (tid & 7) * 8;
            float4 y0 = *(const float4*)(Y + (size_t)r2 * K_ + o2);
            float4 y1 = *(const float4*)(Y + (size_t)r2 * K_ + o2 + 4);
            *(float4*)(wrow + (32 + r2) * WSTRIDE + o2)     = y0;
            *(float4*)(wrow + (32 + r2) * WSTRIDE + o2 + 4) = y1;
        }
    }
    __syncthreads();

    const int cA  = (i < NUP_) ? 0 : 1;
    const int tti = i >> 4;                        // tile holding self-row
    const int sil = i & 15;                        // self-row lane
    const int hq  = quad * 4;
    const unsigned int biasu = (quad == 0) ? 0x00003F80u : 0u;   // bf16 1.0 @ p=36

    // ================= electron tiles =================
    #pragma unroll
    for (int t = 0; t < 2; ++t) {
        const int c  = (t == 0) ? cA : 1 - cA;
        const int lc = l * 3 + c;
        const float* wlc = wb1 + (size_t)lc * H_;

        // ---- B-frag (e^T): 8 consecutive f of this lane's edge row ----
        const float* ep = ee + (((size_t)bi * N_) + t * 16 + l16) * F_ + quad * 8;
        float4 fa = *(const float4*)(ep);
        float4 fb = *(const float4*)(ep + 4);
        union { short8 s; unsigned int u[4]; } E;
        E.u[0] = cvtpk(fa.x, fa.y); E.u[1] = cvtpk(fa.z, fa.w);
        E.u[2] = cvtpk(fb.x, fb.y); E.u[3] = cvtpk(fb.z, fb.w);

        // ---- stage-1 bias (h contiguous in wb1; guard h>=45, clamp address) ----
        const bool g3 = (hq < 12);
        float4v acc1[3];
        acc1[0] = (float4v){wlc[hq], wlc[hq + 1], wlc[hq + 2], wlc[hq + 3]};
        acc1[1] = (float4v){wlc[16 + hq], wlc[17 + hq], wlc[18 + hq], wlc[19 + hq]};
        {
            float b1 = wlc[g3 ? (33 + hq) : 0];
            float b2 = wlc[g3 ? (34 + hq) : 0];
            float b3 = wlc[g3 ? (35 + hq) : 0];
            acc1[2] = (float4v){wlc[32 + hq], g3 ? b1 : 0.0f, g3 ? b2 : 0.0f, g3 ? b3 : 0.0f};
        }

        // ---- stage 1 swapped: D[h][edge] ----
        #pragma unroll
        for (int nt = 0; nt < 3; ++nt) {
            short8 wf = *(const short8*)(w1B + (((size_t)lc * 3 + nt) << 9) + (lane << 3));
            acc1[nt] = __builtin_amdgcn_mfma_f32_16x16x32_bf16(wf, E.s, acc1[nt], 0, 0, 0);
        }

        // ---- ssp + pack straight into stage-2 A-frags (no LDS) ----
        union { short8 s; unsigned int u[4]; } A0, A1;
        A0.u[0] = cvtpk(ssp(acc1[0][0]), ssp(acc1[0][1]));
        A0.u[1] = cvtpk(ssp(acc1[0][2]), ssp(acc1[0][3]));
        A0.u[2] = cvtpk(ssp(acc1[1][0]), ssp(acc1[1][1]));
        A0.u[3] = cvtpk(ssp(acc1[1][2]), ssp(acc1[1][3]));
        A1.u[0] = cvtpk(ssp(acc1[2][0]), ssp(acc1[2][1]));
        A1.u[1] = cvtpk(ssp(acc1[2][2]), ssp(acc1[2][3]));
        A1.u[2] = biasu;
        A1.u[3] = 0u;
        const bool deadl = (t == tti) && (l16 == sil);   // self-edge: zero whole row
        if (deadl) {
            A0.u[0] = 0u; A0.u[1] = 0u; A0.u[2] = 0u; A0.u[3] = 0u;
            A1.u[0] = 0u; A1.u[1] = 0u; A1.u[2] = 0u;
        }

        // ---- stage 2: two K-steps, bias via p=36 slot ----
        float4v acc2[4];
        #pragma unroll
        for (int nt = 0; nt < 4; ++nt) acc2[nt] = (float4v){0.f, 0.f, 0.f, 0.f};
        #pragma unroll
        for (int nt = 0; nt < 4; ++nt) {
            short8 bf0 = *(const short8*)(w2B + ((((size_t)lc * 2 + 0) * 4 + nt) << 9) + (lane << 3));
            acc2[nt] = __builtin_amdgcn_mfma_f32_16x16x32_bf16(A0.s, bf0, acc2[nt], 0, 0, 0);
            short8 bf1 = *(const short8*)(w2B + ((((size_t)lc * 2 + 1) * 4 + nt) << 9) + (lane << 3));
            acc2[nt] = __builtin_amdgcn_mfma_f32_16x16x32_bf16(A1.s, bf1, acc2[nt], 0, 0, 0);
        }

        // ---- epilogue: msg * h(j,k), sum over rows — unmasked (dead row is 0) ----
        float p0 = 0.f, p1 = 0.f, p2 = 0.f, p3 = 0.f;
        #pragma unroll
        for (int r = 0; r < 4; ++r) {
            const int jrow = t * 16 + quad * 4 + r;
            const float* wr = wrow + jrow * WSTRIDE + l16;
            p0 += acc2[0][r] * wr[0];
            p1 += acc2[1][r] * wr[16];
            p2 += acc2[2][r] * wr[32];
            p3 += acc2[3][r] * wr[48];
        }

        // ---- butterfly reduce with value swap: 3 shuffles, no final select ----
        const bool qlo = (quad & 1) != 0;
        const bool qhi = (quad & 2) != 0;
        float u  = qlo ? p1 : p0;
        float us = qlo ? p0 : p1;
        u += __shfl_xor(us, 16);
        float w  = qlo ? p3 : p2;
        float ws = qlo ? p2 : p3;
        w += __shfl_xor(ws, 16);
        float v  = qhi ? w : u;
        float vs = qhi ? u : w;
        v += __shfl_xor(vs, 32);

        zb[(size_t)bi * 192 + c * 64 + lane] = (unsigned short)cvtpk(v, v);
    }

    // ================= nuclear tile: wave 0 only, 4 i's x 4 m's =================
    if (wv == 0) {
        const int lc = l * 3 + 2;
        const float* wlc = wb1 + (size_t)lc * H_;

        // edge row l16 = 4*local_i + m  ->  en[bi*4 + l16]
        const float* np = en + ((size_t)bi * M_ + l16) * F_ + quad * 8;
        float4 fa = *(const float4*)(np);
        float4 fb = *(const float4*)(np + 4);
        union { short8 s; unsigned int u[4]; } E;
        E.u[0] = cvtpk(fa.x, fa.y); E.u[1] = cvtpk(fa.z, fa.w);
        E.u[2] = cvtpk(fb.x, fb.y); E.u[3] = cvtpk(fb.z, fb.w);

        const bool g3 = (hq < 12);
        float4v acc1[3];
        acc1[0] = (float4v){wlc[hq], wlc[hq + 1], wlc[hq + 2], wlc[hq + 3]};
        acc1[1] = (float4v){wlc[16 + hq], wlc[17 + hq], wlc[18 + hq], wlc[19 + hq]};
        {
            float b1 = wlc[g3 ? (33 + hq) : 0];
            float b2 = wlc[g3 ? (34 + hq) : 0];
            float b3 = wlc[g3 ? (35 + hq) : 0];
            acc1[2] = (float4v){wlc[32 + hq], g3 ? b1 : 0.0f, g3 ? b2 : 0.0f, g3 ? b3 : 0.0f};
        }
        #pragma unroll
        for (int nt = 0; nt < 3; ++nt) {
            short8 wf = *(const short8*)(w1B + (((size_t)lc * 3 + nt) << 9) + (lane << 3));
            acc1[nt] = __builtin_amdgcn_mfma_f32_16x16x32_bf16(wf, E.s, acc1[nt], 0, 0, 0);
        }

        union { short8 s; unsigned int u[4]; } A0, A1;
        A0.u[0] = cvtpk(ssp(acc1[0][0]), ssp(acc1[0][1]));
        A0.u[1] = cvtpk(ssp(acc1[0][2]), ssp(acc1[0][3]));
        A0.u[2] = cvtpk(ssp(acc1[1][0]), ssp(acc1[1][1]));
        A0.u[3] = cvtpk(ssp(acc1[1][2]), ssp(acc1[1][3]));
        A1.u[0] = cvtpk(ssp(acc1[2][0]), ssp(acc1[2][1]));
        A1.u[1] = cvtpk(ssp(acc1[2][2]), ssp(acc1[2][3]));
        A1.u[2] = biasu;
        A1.u[3] = 0u;

        float4v acc2[4];
        #pragma unroll
        for (int nt = 0; nt < 4; ++nt) acc2[nt] = (float4v){0.f, 0.f, 0.f, 0.f};
        #pragma unroll
        for (int nt = 0; nt < 4; ++nt) {
            short8 bf0 = *(const short8*)(w2B + ((((size_t)lc * 2 + 0) * 4 + nt) << 9) + (lane << 3));
            acc2[nt] = __builtin_amdgcn_mfma_f32_16x16x32_bf16(A0.s, bf0, acc2[nt], 0, 0, 0);
            short8 bf1 = *(const short8*)(w2B + ((((size_t)lc * 2 + 1) * 4 + nt) << 9) + (lane << 3));
            acc2[nt] = __builtin_amdgcn_mfma_f32_16x16x32_bf16(A1.s, bf1, acc2[nt], 0, 0, 0);
        }

        // acc2[nt][r] = msg[row=quad*4+r][col=nt*16+l16]; row -> (local_i=quad, m=r)
        float p0 = 0.f, p1 = 0.f, p2 = 0.f, p3 = 0.f;
        #pragma unroll
        for (int r = 0; r < 4; ++r) {
            const float* wr = wrow + (32 + r) * WSTRIDE + l16;
            p0 += acc2[0][r] * wr[0];
            p1 += acc2[1][r] * wr[16];
            p2 += acc2[2][r] * wr[32];
            p3 += acc2[3][r] * wr[48];
        }
        unsigned short* zo = zb + (size_t)(bi + quad) * 192 + 128 + l16;
        zo[0]  = (unsigned short)cvtpk(p0, p0);
        zo[16] = (unsigned short)cvtpk(p1, p1);
        zo[32] = (unsigned short)cvtpk(p2, p2);
        zo[48] = (unsigned short)cvtpk(p3, p3);
    }
}

// ---------------- MFMA fuse: x += Z@Gcat^T + gbs; h_next = x@hW^T + hb ----------------
// Wave pairs split the output-column dim: half = wv&1 handles nt0 = half*4 .. +3
// of the x-GEMM and nt2 = half*2 .. +1 of the h-GEMM. 2 row-groups per block.
#define HXS 136   // shorts per hx row
__global__ __launch_bounds__(256) void fuse_kernel(
    const unsigned short* __restrict__ zb, const short* __restrict__ gB,
    const float* __restrict__ gbs, const float* __restrict__ X,
    const short* __restrict__ hB, const float* __restrict__ hb,
    float* __restrict__ xout, float* __restrict__ hout,
    int l, int first, int compute_h)
{
    __shared__ short hx_s[2][16 * HXS];    // 8704 B

    const int tid  = threadIdx.x;
    const int wv   = tid >> 6;
    const int lane = tid & 63;
    const int quad = lane >> 4;
    const int l16  = lane & 15;
    const int pair = wv >> 1;
    const int half = wv & 1;
    const int nt0  = half * 4;
    const int bi0  = (blockIdx.x * 2 + pair) * 16;

    // ---- Z @ Gcat^T : 6 K-steps x 4 column tiles (this wave's half) ----
    float4v ax[4];
    #pragma unroll
    for (int nt = 0; nt < 4; ++nt) ax[nt] = (float4v){0.f, 0.f, 0.f, 0.f};
    const short* gb_ = gB + (size_t)l * 48 * 512;
    const short* zrow = (const short*)zb + ((size_t)(bi0 + l16)) * 192;
    #pragma unroll
    for (int ks = 0; ks < 6; ++ks) {
        short8 az = *(const short8*)(zrow + ks * 32 + quad * 8);
        #pragma unroll
        for (int nt = 0; nt < 4; ++nt) {
            short8 bf = *(const short8*)(gb_ + (((size_t)ks * 8 + nt0 + nt) << 9) + (lane << 3));
            ax[nt] = __builtin_amdgcn_mfma_f32_16x16x32_bf16(az, bf, ax[nt], 0, 0, 0);
        }
    }

    // ---- epilogue: residual + biases, store x, pack bf16 half-rows for h-GEMM ----
    float gv[4], xb[4];
    #pragma unroll
    for (int nt = 0; nt < 4; ++nt) {
        gv[nt] = gbs[(size_t)l * D_ + (nt0 + nt) * 16 + l16];
        if (first) xb[nt] = X[(nt0 + nt) * 16 + l16];
    }
    short* hx = hx_s[pair];
    #pragma unroll
    for (int r = 0; r < 4; ++r) {
        int row = quad * 4 + r;
        size_t gi = ((size_t)(bi0 + row)) * D_ + l16;
        float xv[4];
        #pragma unroll
        for (int nt = 0; nt < 4; ++nt) {
            float xo = (first ? xb[nt] : xout[gi + (nt0 + nt) * 16]) + gv[nt] + ax[nt][r];
            xout[gi + (nt0 + nt) * 16] = xo;
            xv[nt] = xo;
        }
        if (compute_h) {
            uint2 P;
            P.x = cvtpk(xv[0], xv[1]);
            P.y = cvtpk(xv[2], xv[3]);
            *(uint2*)(hx + row * HXS + 8 * l16 + 4 * half) = P;
        }
    }
    if (!compute_h) return;
    __syncthreads();

    // ---- h_next = x @ hW^T : 4 K-steps x 2 column tiles (this wave's half) ----
    float4v ah[2];
    #pragma unroll
    for (int nt = 0; nt < 2; ++nt) ah[nt] = (float4v){0.f, 0.f, 0.f, 0.f};
    const short* hb_ = hB + (size_t)l * 16 * 512;
    #pragma unroll
    for (int ks = 0; ks < 4; ++ks) {
        short8 a = *(const short8*)(hx + l16 * HXS + ks * 32 + quad * 8);
        #pragma unroll
        for (int nt = 0; nt < 2; ++nt) {
            short8 bf = *(const short8*)(hb_ + (((size_t)ks * 4 + half * 2 + nt) << 9) + (lane << 3));
            ah[nt] = __builtin_amdgcn_mfma_f32_16x16x32_bf16(a, bf, ah[nt], 0, 0, 0);
        }
    }
    float hbv[2];
    #pragma unroll
    for (int nt = 0; nt < 2; ++nt) hbv[nt] = hb[((size_t)(l + 1)) * K_ + (half * 2 + nt) * 16 + l16];
    #pragma unroll
    for (int nt = 0; nt < 2; ++nt)
        #pragma unroll
        for (int r = 0; r < 4; ++r)
            hout[((size_t)(bi0 + quad * 4 + r)) * K_ + (half * 2 + nt) * 16 + l16] = ah[nt][r] + hbv[nt];
}

// ---------------- launch ----------------
extern "C" void kernel_launch(void* const* d_in, const int* in_sizes, int n_in,
                              void* d_out, int out_size, void* d_ws, size_t ws_size,
                              hipStream_t stream)
{
    const float* ee  = (const float*)d_in[0];
    const float* en  = (const float*)d_in[1];
    const float* X   = (const float*)d_in[2];
    const float* Y   = (const float*)d_in[3];
    const float* wW1 = (const float*)d_in[4];
    const float* wb1 = (const float*)d_in[5];
    const float* wW2 = (const float*)d_in[6];
    const float* wb2 = (const float*)d_in[7];
    const float* hW  = (const float*)d_in[8];
    const float* hb  = (const float*)d_in[9];
    const float* gW  = (const float*)d_in[10];
    const float* gb  = (const float*)d_in[11];
    float* xout = (float*)d_out;

    // workspace carve (byte offsets, all 16B-aligned) — footprint unchanged
    char* ws = (char*)d_ws;
    float*          h   = (float*)(ws);                         // 8,388,608 B
    unsigned short* zb  = (unsigned short*)(ws + 8388608);      // 12,582,912 B
    float*          h0  = (float*)(ws + 8388608 + 12582912);    // 256 B
    short*          w1B = (short*)(ws + 20971520 + 256);        // 27,648 B
    short*          w2B = w1B + (size_t)27 * 512;               // 73,728 B
    short*          gB  = w2B + (size_t)72 * 512;               // 147,456 B
    short*          hB  = gB  + (size_t)144 * 512;              // 32,768 B
    float*          gbs = (float*)(hB + (size_t)32 * 512);      // 1,536 B

    prep_kernel<<<276, 256, 0, stream>>>(wW1, wb1, wW2, wb2, gW, hW, gb,
                                         w1B, w2B, gB, hB, gbs);
    h0_kernel<<<1, 64, 0, stream>>>(X, hW, hb, h0);

    // layer 0
    edge_kernel<<<8192, 256, 0, stream>>>(ee, en, Y, w1B, wb1, w2B, h, h0, zb, 0, 0);
    fuse_kernel<<<1024, 256, 0, stream>>>(zb, gB, gbs, X, hB, hb, xout, h, 0, 1, 1);
    // layer 1
    edge_kernel<<<8192, 256, 0, stream>>>(ee, en, Y, w1B, wb1, w2B, h, h0, zb, 1, 1);
    fuse_kernel<<<1024, 256, 0, stream>>>(zb, gB, gbs, X, hB, hb, xout, h, 1, 0, 1);
    // layer 2
    edge_kernel<<<8192, 256, 0, stream>>>(ee, en, Y, w1B, wb1, w2B, h, h0, zb, 2, 1);
    fuse_kernel<<<1024, 256, 0, stream>>>(zb, gB, gbs, X, hB, hb, xout, h, 2, 0, 0);
}

// Round 7
// 377.144 us; speedup vs baseline: 1.1138x; 1.0654x over previous
//
#include <hip/hip_runtime.h>
#include <math.h>

// ---------------- problem constants ----------------
#define N_   32
#define NUP_ 16
#define M_   4
#define D_   128
#define K_   64
#define F_   32
#define H_   45
#define L_   3
#define LOG2_ 0.69314718055994530942f

typedef __attribute__((ext_vector_type(8))) short short8;
typedef __attribute__((ext_vector_type(4))) float float4v;

__device__ __forceinline__ float ssp(float v) {
    // softplus(v) - log(2) == log(0.5 + 0.5*e^v); ssp(0) == 0 exactly
    return __logf(fmaf(0.5f, __expf(v), 0.5f));
}

__device__ __forceinline__ unsigned short f2bf(float x) {   // RTNE, prep only
    unsigned int u = __float_as_uint(x);
    return (unsigned short)((u + 0x7FFFu + ((u >> 16) & 1u)) >> 16);
}

// pack two floats -> bf16x2 in ONE VALU op (RTNE)
__device__ __forceinline__ unsigned int cvtpk(float x, float y) {
    unsigned int r;
    asm("v_cvt_pk_bf16_f32 %0, %1, %2" : "=v"(r) : "v"(x), "v"(y));
    return r;
}

// ---------------- prep: pack all weights into MFMA B-fragment order ----------------
// w1B[lc][nt:3][512]   frag: k=(lane>>4)*8+jj (f), row/col idx = nt*16+(lane&15) (hidden)
// w2B[lc][ks:2][nt:4][512]  B-frag: k=p, n=kout.  p-map for REGISTER-DIRECT stage 2:
//                      p<32:  h = (j>>2)*16 + q*4 + (j&3)   (q=p>>3, j=p&7)
//                      p>=32, j<4: h = 32 + q*4 + j
//                      p==36: bias row (pairs with A-frag const 1.0); else zero
// gB [l][ks:6][nt:8][512]   k=c*64+kk, n=d
// hB [li:2][ks:4][nt2:4][512] k=p, d=(p&7)*16+(p>>3), n=kout   (hW layers 1,2)
// gbs[l][128] = sum_c gb[l][c][:]
__global__ __launch_bounds__(256) void prep_kernel(
    const float* __restrict__ wW1, const float* __restrict__ wb1_unused,
    const float* __restrict__ wW2, const float* __restrict__ wb2,
    const float* __restrict__ gW,  const float* __restrict__ hW,
    const float* __restrict__ gb,
    short* __restrict__ w1B, short* __restrict__ w2B,
    short* __restrict__ gB,  short* __restrict__ hB, float* __restrict__ gbs)
{
    int blk = blockIdx.x;
    int t = threadIdx.x;
    if (blk < 27) {                       // w1B
        int lc = blk / 3, nt = blk % 3;
        short* dst = w1B + (size_t)blk * 512;
        for (int idx = t; idx < 512; idx += 256) {
            int lane = idx >> 3, jj = idx & 7;
            int k = ((lane >> 4) << 3) + jj;
            int n = nt * 16 + (lane & 15);
            float v = (n < H_) ? wW1[((size_t)lc * H_ + n) * F_ + k] : 0.0f;
            dst[idx] = (short)f2bf(v);
        }
    } else if (blk < 99) {                // w2B (register-direct p-map)
        int b3 = blk - 27;
        int lc = b3 >> 3, rem = b3 & 7, ks = rem >> 2, nt = rem & 3;
        short* dst = w2B + (size_t)b3 * 512;
        for (int idx = t; idx < 512; idx += 256) {
            int lane = idx >> 3, jj = idx & 7;
            int p = ks * 32 + ((lane >> 4) << 3) + jj;
            int n = nt * 16 + (lane & 15);
            int q = (p & 31) >> 3, j = p & 7;
            float v;
            if (p < 32) {
                int u = (j >> 2) * 16 + q * 4 + (j & 3);    // h < 32, always valid
                v = wW2[((size_t)lc * K_ + n) * H_ + u];
            } else if (j < 4) {
                int u = 32 + q * 4 + j;
                v = (u < H_) ? wW2[((size_t)lc * K_ + n) * H_ + u] : 0.0f;
            } else if (p == 36) {
                v = wb2[(size_t)lc * K_ + n];
            } else v = 0.0f;
            dst[idx] = (short)f2bf(v);
        }
    } else if (blk < 243) {               // gB
        int g = blk - 99;
        int l = g / 48, rem = g % 48;     // rem = ks*8+nt
        short* dst = gB + (size_t)g * 512;
        for (int idx = t; idx < 512; idx += 256) {
            int lane = idx >> 3, jj = idx & 7;
            int k = (rem >> 3) * 32 + ((lane >> 4) << 3) + jj;  // 0..191
            int c = k >> 6, kk = k & 63;
            int n = ((rem & 7) * 16) + (lane & 15);
            dst[idx] = (short)f2bf(gW[(((size_t)l * 3 + c) * D_ + n) * K_ + kk]);
        }
    } else if (blk < 275) {               // hB
        int hh = blk - 243;
        int li = hh >> 4, rem = hh & 15;  // rem = ks*4+nt2
        short* dst = hB + (size_t)hh * 512;
        for (int idx = t; idx < 512; idx += 256) {
            int lane = idx >> 3, jj = idx & 7;
            int p = (rem >> 2) * 32 + ((lane >> 4) << 3) + jj;  // 0..127
            int d = (p & 7) * 16 + (p >> 3);
            int n = ((rem & 3) * 16) + (lane & 15);
            dst[idx] = (short)f2bf(hW[(((size_t)(li + 1)) * K_ + n) * D_ + d]);
        }
    } else {                              // gbs
        for (int idx = t; idx < 384; idx += 256) {
            int l = idx >> 7, d = idx & 127;
            gbs[idx] = gb[((size_t)l * 3 + 0) * D_ + d]
                     + gb[((size_t)l * 3 + 1) * D_ + d]
                     + gb[((size_t)l * 3 + 2) * D_ + d];
        }
    }
}

// ---------------- h0: layer-0 h is a single broadcast row ----------------
__global__ __launch_bounds__(64) void h0_kernel(
    const float* __restrict__ X, const float* __restrict__ hW,
    const float* __restrict__ hb, float* __restrict__ h0)
{
    int k = threadIdx.x;
    float a = hb[k];
    const float* w = hW + (size_t)k * D_;
    #pragma unroll 8
    for (int dd = 0; dd < D_; ++dd) a += w[dd] * X[dd];
    h0[k] = a;
}

// ---------------- MFMA edge kernel: 4 waves/WG, TWO (b,i) per wave ----------------
// Each wave handles i_a = ig+wv and i_b = ig+wv+4 (same b, same spin-half so the
// channel c — and thus all weight fragments — are SHARED between the two chains).
// Stage 1 swapped (S^T = W1 @ e^T) keeps activations in registers; stage 2 is
// register-direct. The 11 weight loads and 16 epilogue wrow reads serve BOTH
// electrons; the two ssp/MFMA chains interleave to hide latency (r6: 50% stall).
// launch_bounds(256,5): cap ~102 regs = today's achieved occupancy, no TLP loss.
#define WSTRIDE 68     // f32 words per wrow row
__global__ __launch_bounds__(256, 5) void edge_kernel(
    const float* __restrict__ ee, const float* __restrict__ en,
    const float* __restrict__ Y,
    const short* __restrict__ w1B, const float* __restrict__ wb1,
    const short* __restrict__ w2B,
    const float* __restrict__ h, const float* __restrict__ h0,
    unsigned short* __restrict__ zb, int l, int hmode)
{
    __shared__ float wrow[36 * WSTRIDE];          // 9792 B (h rows 0..31, Y rows 32..35)

    const int tid  = threadIdx.x;
    const int wv   = tid >> 6;
    const int lane = tid & 63;
    const int quad = lane >> 4;
    const int l16  = lane & 15;
    const int b    = blockIdx.x >> 2;
    const int ig   = (blockIdx.x & 3) << 3;       // 8 i's per block
    const int ia   = ig + wv;
    const int ib   = ia + 4;
    const size_t bia = (size_t)(b << 5) + ia;
    const size_t bib = (size_t)(b << 5) + ib;

    // ---- stage wrow cooperatively ----
    {
        int row = tid >> 3;
        int col = (tid & 7) * 8;
        const float* src = hmode ? (h + ((size_t)(b * N_ + row)) * K_ + col) : (h0 + col);
        float4 v0 = *(const float4*)(src);
        float4 v1 = *(const float4*)(src + 4);
        *(float4*)(wrow + row * WSTRIDE + col)     = v0;
        *(float4*)(wrow + row * WSTRIDE + col + 4) = v1;
        if (tid < 32) {
            int r2 = tid >> 3, o2 = (tid & 7) * 8;
            float4 y0 = *(const float4*)(Y + (size_t)r2 * K_ + o2);
            float4 y1 = *(const float4*)(Y + (size_t)r2 * K_ + o2 + 4);
            *(float4*)(wrow + (32 + r2) * WSTRIDE + o2)     = y0;
            *(float4*)(wrow + (32 + r2) * WSTRIDE + o2 + 4) = y1;
        }
    }
    __syncthreads();

    const int cA   = (ia < NUP_) ? 0 : 1;          // ia,ib in same half -> shared
    const int ttia = ia >> 4, sila = ia & 15;
    const int ttib = ib >> 4, silb = ib & 15;
    const int hq   = quad * 4;
    const unsigned int biasu = (quad == 0) ? 0x00003F80u : 0u;   // bf16 1.0 @ p=36

    // ================= electron tiles (two i's per wave) =================
    #pragma unroll
    for (int t = 0; t < 2; ++t) {
        const int c  = (t == 0) ? cA : 1 - cA;
        const int lc = l * 3 + c;
        const float* wlc = wb1 + (size_t)lc * H_;

        // ---- B-frags (e^T): lane's edge row for each i ----
        const float* epa = ee + ((bia * N_) + t * 16 + l16) * F_ + quad * 8;
        const float* epb = ee + ((bib * N_) + t * 16 + l16) * F_ + quad * 8;
        float4 fa0 = *(const float4*)(epa);
        float4 fa1 = *(const float4*)(epa + 4);
        float4 fb0 = *(const float4*)(epb);
        float4 fb1 = *(const float4*)(epb + 4);
        union { short8 s; unsigned int u[4]; } Ea, Eb;
        Ea.u[0] = cvtpk(fa0.x, fa0.y); Ea.u[1] = cvtpk(fa0.z, fa0.w);
        Ea.u[2] = cvtpk(fa1.x, fa1.y); Ea.u[3] = cvtpk(fa1.z, fa1.w);
        Eb.u[0] = cvtpk(fb0.x, fb0.y); Eb.u[1] = cvtpk(fb0.z, fb0.w);
        Eb.u[2] = cvtpk(fb1.x, fb1.y); Eb.u[3] = cvtpk(fb1.z, fb1.w);

        // ---- stage-1 bias (shared): h contiguous in wb1; guard h>=45 ----
        const bool g3 = (hq < 12);
        float4v bias0 = (float4v){wlc[hq], wlc[hq + 1], wlc[hq + 2], wlc[hq + 3]};
        float4v bias1 = (float4v){wlc[16 + hq], wlc[17 + hq], wlc[18 + hq], wlc[19 + hq]};
        float4v bias2;
        {
            float b1 = wlc[g3 ? (33 + hq) : 0];
            float b2 = wlc[g3 ? (34 + hq) : 0];
            float b3 = wlc[g3 ? (35 + hq) : 0];
            bias2 = (float4v){wlc[32 + hq], g3 ? b1 : 0.0f, g3 ? b2 : 0.0f, g3 ? b3 : 0.0f};
        }

        // ---- stage 1 swapped: shared W1 fragment feeds both chains ----
        float4v acc1a[3], acc1b[3];
        acc1a[0] = bias0; acc1a[1] = bias1; acc1a[2] = bias2;
        acc1b[0] = bias0; acc1b[1] = bias1; acc1b[2] = bias2;
        #pragma unroll
        for (int nt = 0; nt < 3; ++nt) {
            short8 wf = *(const short8*)(w1B + (((size_t)lc * 3 + nt) << 9) + (lane << 3));
            acc1a[nt] = __builtin_amdgcn_mfma_f32_16x16x32_bf16(wf, Ea.s, acc1a[nt], 0, 0, 0);
            acc1b[nt] = __builtin_amdgcn_mfma_f32_16x16x32_bf16(wf, Eb.s, acc1b[nt], 0, 0, 0);
        }

        // ---- ssp + pack straight into stage-2 A-frags (two independent chains) ----
        union { short8 s; unsigned int u[4]; } A0a, A1a, A0b, A1b;
        A0a.u[0] = cvtpk(ssp(acc1a[0][0]), ssp(acc1a[0][1]));
        A0a.u[1] = cvtpk(ssp(acc1a[0][2]), ssp(acc1a[0][3]));
        A0a.u[2] = cvtpk(ssp(acc1a[1][0]), ssp(acc1a[1][1]));
        A0a.u[3] = cvtpk(ssp(acc1a[1][2]), ssp(acc1a[1][3]));
        A1a.u[0] = cvtpk(ssp(acc1a[2][0]), ssp(acc1a[2][1]));
        A1a.u[1] = cvtpk(ssp(acc1a[2][2]), ssp(acc1a[2][3]));
        A1a.u[2] = biasu; A1a.u[3] = 0u;
        A0b.u[0] = cvtpk(ssp(acc1b[0][0]), ssp(acc1b[0][1]));
        A0b.u[1] = cvtpk(ssp(acc1b[0][2]), ssp(acc1b[0][3]));
        A0b.u[2] = cvtpk(ssp(acc1b[1][0]), ssp(acc1b[1][1]));
        A0b.u[3] = cvtpk(ssp(acc1b[1][2]), ssp(acc1b[1][3]));
        A1b.u[0] = cvtpk(ssp(acc1b[2][0]), ssp(acc1b[2][1]));
        A1b.u[1] = cvtpk(ssp(acc1b[2][2]), ssp(acc1b[2][3]));
        A1b.u[2] = biasu; A1b.u[3] = 0u;
        if ((t == ttia) && (l16 == sila)) {          // self-edge of i_a
            A0a.u[0] = 0u; A0a.u[1] = 0u; A0a.u[2] = 0u; A0a.u[3] = 0u;
            A1a.u[0] = 0u; A1a.u[1] = 0u; A1a.u[2] = 0u;
        }
        if ((t == ttib) && (l16 == silb)) {          // self-edge of i_b
            A0b.u[0] = 0u; A0b.u[1] = 0u; A0b.u[2] = 0u; A0b.u[3] = 0u;
            A1b.u[0] = 0u; A1b.u[1] = 0u; A1b.u[2] = 0u;
        }

        // ---- stage 2: shared W2 fragments, 16 MFMAs total ----
        float4v acc2a[4], acc2b[4];
        #pragma unroll
        for (int nt = 0; nt < 4; ++nt) {
            acc2a[nt] = (float4v){0.f, 0.f, 0.f, 0.f};
            acc2b[nt] = (float4v){0.f, 0.f, 0.f, 0.f};
        }
        #pragma unroll
        for (int nt = 0; nt < 4; ++nt) {
            short8 bf0 = *(const short8*)(w2B + ((((size_t)lc * 2 + 0) * 4 + nt) << 9) + (lane << 3));
            acc2a[nt] = __builtin_amdgcn_mfma_f32_16x16x32_bf16(A0a.s, bf0, acc2a[nt], 0, 0, 0);
            acc2b[nt] = __builtin_amdgcn_mfma_f32_16x16x32_bf16(A0b.s, bf0, acc2b[nt], 0, 0, 0);
            short8 bf1 = *(const short8*)(w2B + ((((size_t)lc * 2 + 1) * 4 + nt) << 9) + (lane << 3));
            acc2a[nt] = __builtin_amdgcn_mfma_f32_16x16x32_bf16(A1a.s, bf1, acc2a[nt], 0, 0, 0);
            acc2b[nt] = __builtin_amdgcn_mfma_f32_16x16x32_bf16(A1b.s, bf1, acc2b[nt], 0, 0, 0);
        }

        // ---- epilogue: shared wrow reads feed both accumulator sets ----
        float pa0 = 0.f, pa1 = 0.f, pa2 = 0.f, pa3 = 0.f;
        float pb0 = 0.f, pb1 = 0.f, pb2 = 0.f, pb3 = 0.f;
        #pragma unroll
        for (int r = 0; r < 4; ++r) {
            const int jrow = t * 16 + quad * 4 + r;
            const float* wr = wrow + jrow * WSTRIDE + l16;
            float w0 = wr[0], w1 = wr[16], w2 = wr[32], w3 = wr[48];
            pa0 += acc2a[0][r] * w0;  pb0 += acc2b[0][r] * w0;
            pa1 += acc2a[1][r] * w1;  pb1 += acc2b[1][r] * w1;
            pa2 += acc2a[2][r] * w2;  pb2 += acc2b[2][r] * w2;
            pa3 += acc2a[3][r] * w3;  pb3 += acc2b[3][r] * w3;
        }

        // ---- butterfly reduce with value swap (per i): 3 shuffles each ----
        const bool qlo = (quad & 1) != 0;
        const bool qhi = (quad & 2) != 0;
        {
            float u  = qlo ? pa1 : pa0;
            float us = qlo ? pa0 : pa1;
            u += __shfl_xor(us, 16);
            float w  = qlo ? pa3 : pa2;
            float ws = qlo ? pa2 : pa3;
            w += __shfl_xor(ws, 16);
            float v  = qhi ? w : u;
            float vs = qhi ? u : w;
            v += __shfl_xor(vs, 32);
            zb[bia * 192 + c * 64 + lane] = (unsigned short)cvtpk(v, v);
        }
        {
            float u  = qlo ? pb1 : pb0;
            float us = qlo ? pb0 : pb1;
            u += __shfl_xor(us, 16);
            float w  = qlo ? pb3 : pb2;
            float ws = qlo ? pb2 : pb3;
            w += __shfl_xor(ws, 16);
            float v  = qhi ? w : u;
            float vs = qhi ? u : w;
            v += __shfl_xor(vs, 32);
            zb[bib * 192 + c * 64 + lane] = (unsigned short)cvtpk(v, v);
        }
    }

    // ================= nuclear tiles: waves 0,1 — 4 i's x 4 m's each =================
    if (wv < 2) {
        const int lc = l * 3 + 2;
        const float* wlc = wb1 + (size_t)lc * H_;
        const size_t nbase = (size_t)(b << 5) + ig + (wv << 2);

        // edge row l16 = 4*local_i + m  ->  en[(nbase + local_i)*4 + m] = en[nbase*4 + l16]
        const float* np = en + (nbase * M_ + l16) * F_ + quad * 8;
        float4 fa = *(const float4*)(np);
        float4 fb = *(const float4*)(np + 4);
        union { short8 s; unsigned int u[4]; } E;
        E.u[0] = cvtpk(fa.x, fa.y); E.u[1] = cvtpk(fa.z, fa.w);
        E.u[2] = cvtpk(fb.x, fb.y); E.u[3] = cvtpk(fb.z, fb.w);

        const bool g3 = (hq < 12);
        float4v acc1[3];
        acc1[0] = (float4v){wlc[hq], wlc[hq + 1], wlc[hq + 2], wlc[hq + 3]};
        acc1[1] = (float4v){wlc[16 + hq], wlc[17 + hq], wlc[18 + hq], wlc[19 + hq]};
        {
            float b1 = wlc[g3 ? (33 + hq) : 0];
            float b2 = wlc[g3 ? (34 + hq) : 0];
            float b3 = wlc[g3 ? (35 + hq) : 0];
            acc1[2] = (float4v){wlc[32 + hq], g3 ? b1 : 0.0f, g3 ? b2 : 0.0f, g3 ? b3 : 0.0f};
        }
        #pragma unroll
        for (int nt = 0; nt < 3; ++nt) {
            short8 wf = *(const short8*)(w1B + (((size_t)lc * 3 + nt) << 9) + (lane << 3));
            acc1[nt] = __builtin_amdgcn_mfma_f32_16x16x32_bf16(wf, E.s, acc1[nt], 0, 0, 0);
        }

        union { short8 s; unsigned int u[4]; } A0, A1;
        A0.u[0] = cvtpk(ssp(acc1[0][0]), ssp(acc1[0][1]));
        A0.u[1] = cvtpk(ssp(acc1[0][2]), ssp(acc1[0][3]));
        A0.u[2] = cvtpk(ssp(acc1[1][0]), ssp(acc1[1][1]));
        A0.u[3] = cvtpk(ssp(acc1[1][2]), ssp(acc1[1][3]));
        A1.u[0] = cvtpk(ssp(acc1[2][0]), ssp(acc1[2][1]));
        A1.u[1] = cvtpk(ssp(acc1[2][2]), ssp(acc1[2][3]));
        A1.u[2] = biasu;
        A1.u[3] = 0u;

        float4v acc2[4];
        #pragma unroll
        for (int nt = 0; nt < 4; ++nt) acc2[nt] = (float4v){0.f, 0.f, 0.f, 0.f};
        #pragma unroll
        for (int nt = 0; nt < 4; ++nt) {
            short8 bf0 = *(const short8*)(w2B + ((((size_t)lc * 2 + 0) * 4 + nt) << 9) + (lane << 3));
            acc2[nt] = __builtin_amdgcn_mfma_f32_16x16x32_bf16(A0.s, bf0, acc2[nt], 0, 0, 0);
            short8 bf1 = *(const short8*)(w2B + ((((size_t)lc * 2 + 1) * 4 + nt) << 9) + (lane << 3));
            acc2[nt] = __builtin_amdgcn_mfma_f32_16x16x32_bf16(A1.s, bf1, acc2[nt], 0, 0, 0);
        }

        // acc2[nt][r] = msg[row=quad*4+r][col=nt*16+l16]; row -> (local_i=quad, m=r)
        float p0 = 0.f, p1 = 0.f, p2 = 0.f, p3 = 0.f;
        #pragma unroll
        for (int r = 0; r < 4; ++r) {
            const float* wr = wrow + (32 + r) * WSTRIDE + l16;
            p0 += acc2[0][r] * wr[0];
            p1 += acc2[1][r] * wr[16];
            p2 += acc2[2][r] * wr[32];
            p3 += acc2[3][r] * wr[48];
        }
        unsigned short* zo = zb + (nbase + quad) * 192 + 128 + l16;
        zo[0]  = (unsigned short)cvtpk(p0, p0);
        zo[16] = (unsigned short)cvtpk(p1, p1);
        zo[32] = (unsigned short)cvtpk(p2, p2);
        zo[48] = (unsigned short)cvtpk(p3, p3);
    }
}

// ---------------- MFMA fuse: x += Z@Gcat^T + gbs; h_next = x@hW^T + hb ----------------
// Wave pairs split the output-column dim: half = wv&1 handles nt0 = half*4 .. +3
// of the x-GEMM and nt2 = half*2 .. +1 of the h-GEMM. 2 row-groups per block.
#define HXS 136   // shorts per hx row
__global__ __launch_bounds__(256) void fuse_kernel(
    const unsigned short* __restrict__ zb, const short* __restrict__ gB,
    const float* __restrict__ gbs, const float* __restrict__ X,
    const short* __restrict__ hB, const float* __restrict__ hb,
    float* __restrict__ xout, float* __restrict__ hout,
    int l, int first, int compute_h)
{
    __shared__ short hx_s[2][16 * HXS];    // 8704 B

    const int tid  = threadIdx.x;
    const int wv   = tid >> 6;
    const int lane = tid & 63;
    const int quad = lane >> 4;
    const int l16  = lane & 15;
    const int pair = wv >> 1;
    const int half = wv & 1;
    const int nt0  = half * 4;
    const int bi0  = (blockIdx.x * 2 + pair) * 16;

    // ---- Z @ Gcat^T : 6 K-steps x 4 column tiles (this wave's half) ----
    float4v ax[4];
    #pragma unroll
    for (int nt = 0; nt < 4; ++nt) ax[nt] = (float4v){0.f, 0.f, 0.f, 0.f};
    const short* gb_ = gB + (size_t)l * 48 * 512;
    const short* zrow = (const short*)zb + ((size_t)(bi0 + l16)) * 192;
    #pragma unroll
    for (int ks = 0; ks < 6; ++ks) {
        short8 az = *(const short8*)(zrow + ks * 32 + quad * 8);
        #pragma unroll
        for (int nt = 0; nt < 4; ++nt) {
            short8 bf = *(const short8*)(gb_ + (((size_t)ks * 8 + nt0 + nt) << 9) + (lane << 3));
            ax[nt] = __builtin_amdgcn_mfma_f32_16x16x32_bf16(az, bf, ax[nt], 0, 0, 0);
        }
    }

    // ---- epilogue: residual + biases, store x, pack bf16 half-rows for h-GEMM ----
    float gv[4], xb[4];
    #pragma unroll
    for (int nt = 0; nt < 4; ++nt) {
        gv[nt] = gbs[(size_t)l * D_ + (nt0 + nt) * 16 + l16];
        if (first) xb[nt] = X[(nt0 + nt) * 16 + l16];
    }
    short* hx = hx_s[pair];
    #pragma unroll
    for (int r = 0; r < 4; ++r) {
        int row = quad * 4 + r;
        size_t gi = ((size_t)(bi0 + row)) * D_ + l16;
        float xv[4];
        #pragma unroll
        for (int nt = 0; nt < 4; ++nt) {
            float xo = (first ? xb[nt] : xout[gi + (nt0 + nt) * 16]) + gv[nt] + ax[nt][r];
            xout[gi + (nt0 + nt) * 16] = xo;
            xv[nt] = xo;
        }
        if (compute_h) {
            uint2 P;
            P.x = cvtpk(xv[0], xv[1]);
            P.y = cvtpk(xv[2], xv[3]);
            *(uint2*)(hx + row * HXS + 8 * l16 + 4 * half) = P;
        }
    }
    if (!compute_h) return;
    __syncthreads();

    // ---- h_next = x @ hW^T : 4 K-steps x 2 column tiles (this wave's half) ----
    float4v ah[2];
    #pragma unroll
    for (int nt = 0; nt < 2; ++nt) ah[nt] = (float4v){0.f, 0.f, 0.f, 0.f};
    const short* hb_ = hB + (size_t)l * 16 * 512;
    #pragma unroll
    for (int ks = 0; ks < 4; ++ks) {
        short8 a = *(const short8*)(hx + l16 * HXS + ks * 32 + quad * 8);
        #pragma unroll
        for (int nt = 0; nt < 2; ++nt) {
            short8 bf = *(const short8*)(hb_ + (((size_t)ks * 4 + half * 2 + nt) << 9) + (lane << 3));
            ah[nt] = __builtin_amdgcn_mfma_f32_16x16x32_bf16(a, bf, ah[nt], 0, 0, 0);
        }
    }
    float hbv[2];
    #pragma unroll
    for (int nt = 0; nt < 2; ++nt) hbv[nt] = hb[((size_t)(l + 1)) * K_ + (half * 2 + nt) * 16 + l16];
    #pragma unroll
    for (int nt = 0; nt < 2; ++nt)
        #pragma unroll
        for (int r = 0; r < 4; ++r)
            hout[((size_t)(bi0 + quad * 4 + r)) * K_ + (half * 2 + nt) * 16 + l16] = ah[nt][r] + hbv[nt];
}

// ---------------- launch ----------------
extern "C" void kernel_launch(void* const* d_in, const int* in_sizes, int n_in,
                              void* d_out, int out_size, void* d_ws, size_t ws_size,
                              hipStream_t stream)
{
    const float* ee  = (const float*)d_in[0];
    const float* en  = (const float*)d_in[1];
    const float* X   = (const float*)d_in[2];
    const float* Y   = (const float*)d_in[3];
    const float* wW1 = (const float*)d_in[4];
    const float* wb1 = (const float*)d_in[5];
    const float* wW2 = (const float*)d_in[6];
    const float* wb2 = (const float*)d_in[7];
    const float* hW  = (const float*)d_in[8];
    const float* hb  = (const float*)d_in[9];
    const float* gW  = (const float*)d_in[10];
    const float* gb  = (const float*)d_in[11];
    float* xout = (float*)d_out;

    // workspace carve (byte offsets, all 16B-aligned) — footprint unchanged
    char* ws = (char*)d_ws;
    float*          h   = (float*)(ws);                         // 8,388,608 B
    unsigned short* zb  = (unsigned short*)(ws + 8388608);      // 12,582,912 B
    float*          h0  = (float*)(ws + 8388608 + 12582912);    // 256 B
    short*          w1B = (short*)(ws + 20971520 + 256);        // 27,648 B
    short*          w2B = w1B + (size_t)27 * 512;               // 73,728 B
    short*          gB  = w2B + (size_t)72 * 512;               // 147,456 B
    short*          hB  = gB  + (size_t)144 * 512;              // 32,768 B
    float*          gbs = (float*)(hB + (size_t)32 * 512);      // 1,536 B

    prep_kernel<<<276, 256, 0, stream>>>(wW1, wb1, wW2, wb2, gW, hW, gb,
                                         w1B, w2B, gB, hB, gbs);
    h0_kernel<<<1, 64, 0, stream>>>(X, hW, hb, h0);

    // layer 0
    edge_kernel<<<4096, 256, 0, stream>>>(ee, en, Y, w1B, wb1, w2B, h, h0, zb, 0, 0);
    fuse_kernel<<<1024, 256, 0, stream>>>(zb, gB, gbs, X, hB, hb, xout, h, 0, 1, 1);
    // layer 1
    edge_kernel<<<4096, 256, 0, stream>>>(ee, en, Y, w1B, wb1, w2B, h, h0, zb, 1, 1);
    fuse_kernel<<<1024, 256, 0, stream>>>(zb, gB, gbs, X, hB, hb, xout, h, 1, 0, 1);
    // layer 2
    edge_kernel<<<4096, 256, 0, stream>>>(ee, en, Y, w1B, wb1, w2B, h, h0, zb, 2, 1);
    fuse_kernel<<<1024, 256, 0, stream>>>(zb, gB, gbs, X, hB, hb, xout, h, 2, 0, 0);
}